// Round 4
// baseline (3062.586 us; speedup 1.0000x reference)
//
#include <hip/hip_runtime.h>
#include <hip/hip_bf16.h>
#include <math.h>

typedef __hip_bfloat16 bf16;
typedef unsigned int u32;

__device__ __forceinline__ float b2f(bf16 x){ return __bfloat162float(x); }
__device__ __forceinline__ bf16  f2b(float x){ return __float2bfloat16(x); }
__device__ __forceinline__ float lo16(u32 u){ return __uint_as_float(u << 16); }
__device__ __forceinline__ float hi16(u32 u){ return __uint_as_float(u & 0xFFFF0000u); }
// float -> bf16 bits with round-to-nearest-even
__device__ __forceinline__ u32 bfbits(float x){
    u32 u = __float_as_uint(x);
    return (u + 0x7FFFu + ((u >> 16) & 1u)) >> 16;
}

#define RSQRT8 0.35355339059327373f
#define G_STEP (10.0f/19.0f)
#define G_COEF (-0.5f/(G_STEP*G_STEP))

// butterfly layout involution: lane l holds head PERM4(l&15); PERM4 is self-inverse
__device__ __forceinline__ constexpr int PERM4(int h){
    return ((h&1)<<3) | ((h&2)<<1) | ((h&4)>>1) | ((h&8)>>3);
}

// fast atan2 for y >= 0 (result in [0, pi]); poly max err ~1.6e-6 rad
__device__ __forceinline__ float fast_atan2(float y, float x){
    float ax = fabsf(x);
    float mn = fminf(y, ax), mx = fmaxf(y, ax);
    float t = mn / fmaxf(mx, 1e-30f);
    float s = t*t;
    float p = t * (0.99997726f + s*(-0.33262347f + s*(0.19354346f +
              s*(-0.11643287f + s*(0.05265332f + s*(-0.01172120f))))));
    float r = (y > ax) ? (1.5707963267948966f - p) : p;
    r = (x < 0.f) ? (3.14159265358979323f - r) : r;
    return r;
}

// inputs are PROVEN f32 (R1/R2 bf16 interpretation -> NaN; R3/R4 probe-selected f32 -> pass)

// ---------------- seg starts (idx_ji sorted) ----------------
__global__ void seg_start_kernel(const int* __restrict__ idx_ji, int T,
                                 int* __restrict__ seg, int E)
{
    int e = blockIdx.x * blockDim.x + threadIdx.x;
    if (e > E) return;
    int lo = 0, hi = T;
    while (lo < hi) { int mid = (lo + hi) >> 1; if (idx_ji[mid] < e) lo = mid + 1; else hi = mid; }
    seg[e] = lo;
}

__global__ void marker_kernel(float* out, int n){
    int i = blockIdx.x * blockDim.x + threadIdx.x;
    if (i < n) out[i] = 12345.0f;
}

// ---------------- pack W2 matrices to bf16-pair layouts (L2-resident) --------
// kw2t[c*64 + p]  = (Wk2[2p][c],  Wk2[2p+1][c])   (Gk compute: lane = p)
// vw2t[j*128 + o] = (Wv2[2j][o],  Wv2[2j+1][o])   (projection: lane = o)
__global__ void pack_w2(const float* __restrict__ Wk2, const float* __restrict__ Wv2,
                        u32* __restrict__ kw2t, u32* __restrict__ vw2t)
{
    int idx = blockIdx.x*256 + threadIdx.x;
    if (idx >= 8192) return;
    int c = idx >> 6, p = idx & 63;
    kw2t[idx] = bfbits(Wk2[(size_t)(2*p)*128 + c]) | (bfbits(Wk2[(size_t)(2*p+1)*128 + c]) << 16);
    int j = idx >> 7, o = idx & 127;
    vw2t[idx] = bfbits(Wv2[(size_t)(2*j)*128 + o]) | (bfbits(Wv2[(size_t)(2*j+1)*128 + o]) << 16);
}

// ---------------- q = MLP_hq(h_bond) per edge -> bf16, 4-edge batched --------
// weight ds_reads amortized x4; 3 barriers per 4 edges (was 2 per edge);
// phase 2 (W2 matvec) barrier-free
__global__ __launch_bounds__(128) void q_kernel(
    const float* __restrict__ W1, const float* __restrict__ B1,
    const float* __restrict__ G,  const float* __restrict__ Bln,
    const float* __restrict__ W2, const float* __restrict__ B2,
    const float* __restrict__ h_bond, bf16* __restrict__ qout, int E)
{
    __shared__ u32 sW[128*65];       // [dim][row-pair] packed bf16, row stride 130 bf16
    __shared__ float sH[16][130];
    __shared__ float sX[4][130];
    __shared__ float sRed[4][4];
    int tid = threadIdx.x; int wv = tid>>6, lane = tid&63;
    int base = blockIdx.x * 16;

    for (int idx = tid; idx < 128*128; idx += 128) {
        int i = idx >> 7, d = idx & 127;
        ((bf16*)sW)[d*130 + i] = f2b(W1[idx]);
    }
    __syncthreads();
    for (int e4 = 0; e4 < 16; e4 += 4) {
        #pragma unroll
        for (int q = 0; q < 4; ++q) {
            int e = base + e4 + q;
            sX[q][tid] = (e < E) ? h_bond[(size_t)e*128 + tid] : 0.f;
        }
        __syncthreads();
        float b1t = B1[tid];
        float ac[4] = {b1t, b1t, b1t, b1t};
        const u32* wrow = &sW[tid*65];
        #pragma unroll 4
        for (int j = 0; j < 64; ++j) {
            u32 w = wrow[j]; float wl = lo16(w), wh = hi16(w);
            #pragma unroll
            for (int q = 0; q < 4; ++q)
                ac[q] += sX[q][2*j]*wl + sX[q][2*j+1]*wh;
        }
        // 4 interleaved (sum, sumsq) wave reductions
        float s1v[4], s2v[4];
        #pragma unroll
        for (int q = 0; q < 4; ++q) { s1v[q] = ac[q]; s2v[q] = ac[q]*ac[q]; }
        #pragma unroll
        for (int m = 1; m < 64; m <<= 1) {
            #pragma unroll
            for (int q = 0; q < 4; ++q) {
                s1v[q] += __shfl_xor(s1v[q], m, 64);
                s2v[q] += __shfl_xor(s2v[q], m, 64);
            }
        }
        if (lane == 0) {
            #pragma unroll
            for (int q = 0; q < 4; ++q) { sRed[q][wv*2] = s1v[q]; sRed[q][wv*2+1] = s2v[q]; }
        }
        __syncthreads();
        float gt = G[tid], bt = Bln[tid];
        #pragma unroll
        for (int q = 0; q < 4; ++q) {
            float tot = sRed[q][0] + sRed[q][2], tot2 = sRed[q][1] + sRed[q][3];
            float mu = tot * (1.f/128.f);
            float var = fmaxf(tot2 * (1.f/128.f) - mu*mu, 0.f);
            float nv = gt * (ac[q] - mu) * rsqrtf(var + 1e-5f) + bt;
            sH[e4+q][tid] = fmaxf(nv, 0.f);
        }
        __syncthreads();
    }
    for (int idx = tid; idx < 128*128; idx += 128) {
        int i = idx >> 7, d = idx & 127;
        ((bf16*)sW)[d*130 + i] = f2b(W2[idx]);
    }
    __syncthreads();
    for (int e4 = 0; e4 < 16; e4 += 4) {
        float b2t = B2[tid];
        float ac[4] = {b2t, b2t, b2t, b2t};
        const u32* wrow = &sW[tid*65];
        #pragma unroll 4
        for (int j = 0; j < 64; ++j) {
            u32 w = wrow[j]; float wl = lo16(w), wh = hi16(w);
            #pragma unroll
            for (int q = 0; q < 4; ++q)
                ac[q] += sH[e4+q][2*j]*wl + sH[e4+q][2*j+1]*wh;
        }
        #pragma unroll
        for (int q = 0; q < 4; ++q) {
            int e = base + e4 + q;
            if (e < E) qout[(size_t)e*128 + tid] = f2b(ac[q]);
        }
    }
}

// ---------------- P1[e] = h_bond[e]@W1[0:128] + rfeat[e]@W1[128:148] -> bf16 --
// 4-edge batched: weight ds_reads amortized x4, 2 barriers per 4 edges, 4 indep FMA chains
__global__ __launch_bounds__(128) void p_prep(
    const float* __restrict__ W1, const float* __restrict__ h_bond,
    const float* __restrict__ pos, const int* __restrict__ row,
    const int* __restrict__ col, bf16* __restrict__ P1, int E)
{
    __shared__ u32 sW[128*75];       // [dim][row-pair], 148 rows -> 74 pairs, stride 150 bf16
    __shared__ float sX[4][152];
    int tid = threadIdx.x;
    for (int idx = tid; idx < 148*128; idx += 128) {
        int i = idx >> 7, d = idx & 127;
        ((bf16*)sW)[d*150 + i] = f2b(W1[idx]);
    }
    __syncthreads();
    int base = blockIdx.x * 16;
    for (int e4 = 0; e4 < 16; e4 += 4) {
        #pragma unroll
        for (int q = 0; q < 4; ++q) {
            int e = base + e4 + q;
            sX[q][tid] = (e < E) ? h_bond[(size_t)e*128 + tid] : 0.f;
        }
        if (tid < 80) {
            int q = tid / 20, g = tid % 20;
            int e = base + e4 + q;
            float rf = 0.f;
            if (e < E) {
                int i0 = col[e], j0 = row[e];
                float dx = pos[(size_t)i0*3+0] - pos[(size_t)j0*3+0];
                float dy = pos[(size_t)i0*3+1] - pos[(size_t)j0*3+1];
                float dz = pos[(size_t)i0*3+2] - pos[(size_t)j0*3+2];
                float dist = sqrtf(dx*dx + dy*dy + dz*dz);
                float t = dist - (float)g * G_STEP;
                rf = __expf(G_COEF * t * t);
            }
            sX[q][128 + g] = rf;
        }
        __syncthreads();
        float acc0 = 0.f, acc1 = 0.f, acc2 = 0.f, acc3 = 0.f;
        const u32* wrow = &sW[tid*75];
        #pragma unroll 4
        for (int j = 0; j < 74; ++j) {
            u32 w = wrow[j]; float wl = lo16(w), wh = hi16(w);
            acc0 += sX[0][2*j]*wl + sX[0][2*j+1]*wh;
            acc1 += sX[1][2*j]*wl + sX[1][2*j+1]*wh;
            acc2 += sX[2][2*j]*wl + sX[2][2*j+1]*wh;
            acc3 += sX[3][2*j]*wl + sX[3][2*j+1]*wh;
        }
        int e = base + e4;
        if (e   < E) P1[(size_t)e*128     + tid] = f2b(acc0);
        if (e+1 < E) P1[(size_t)(e+1)*128 + tid] = f2b(acc1);
        if (e+2 < E) P1[(size_t)(e+2)*128 + tid] = f2b(acc2);
        if (e+3 < E) P1[(size_t)(e+3)*128 + tid] = f2b(acc3);
        __syncthreads();
    }
}

// per-edge setup: P2 pre-act (gaussian part + b1) and 11 DEDUPED angular weight
// pairs in regs. Original 13 features have s1 at {1,4} and c1 at {7,10}: fold
// those weight pairs (f32 add, then one bf16 rounding).
// New feature order: {ang, s1, s2, s3, sh, st3, c1, c2, c3, ch, ct3}
#define EDGE_SETUP(W1full, b1v_, P2a_, P2b_, wa_) \
    float P2a_ = b1v_.x, P2b_ = b1v_.y; \
    { const float2* wbp = (const float2*)((W1full) + (size_t)148*128); \
      for (int g2 = 0; g2 < 20; ++g2) { \
        float tg = dist - (float)g2 * G_STEP; \
        float rf = __expf(G_COEF * tg * tg); \
        float2 wb = wbp[g2*64 + lane]; \
        P2a_ += rf * wb.x; \
        P2b_ += rf * wb.y; \
      } } \
    u32 wa_[11]; \
    { const float2* wap = (const float2*)((W1full) + (size_t)168*128); \
      float2 w0  = wap[ 0*64 + lane]; \
      float2 w1  = wap[ 1*64 + lane]; \
      float2 w2  = wap[ 2*64 + lane]; \
      float2 w3  = wap[ 3*64 + lane]; \
      float2 w4  = wap[ 4*64 + lane]; \
      float2 w5  = wap[ 5*64 + lane]; \
      float2 w6  = wap[ 6*64 + lane]; \
      float2 w7  = wap[ 7*64 + lane]; \
      float2 w8  = wap[ 8*64 + lane]; \
      float2 w9  = wap[ 9*64 + lane]; \
      float2 w10 = wap[10*64 + lane]; \
      float2 w11 = wap[11*64 + lane]; \
      float2 w12 = wap[12*64 + lane]; \
      wa_[0]  = bfbits(w0.x)        | (bfbits(w0.y)        << 16); \
      wa_[1]  = bfbits(w1.x+w4.x)   | (bfbits(w1.y+w4.y)   << 16); \
      wa_[2]  = bfbits(w2.x)        | (bfbits(w2.y)        << 16); \
      wa_[3]  = bfbits(w3.x)        | (bfbits(w3.y)        << 16); \
      wa_[4]  = bfbits(w5.x)        | (bfbits(w5.y)        << 16); \
      wa_[5]  = bfbits(w6.x)        | (bfbits(w6.y)        << 16); \
      wa_[6]  = bfbits(w7.x+w10.x)  | (bfbits(w7.y+w10.y)  << 16); \
      wa_[7]  = bfbits(w8.x)        | (bfbits(w8.y)        << 16); \
      wa_[8]  = bfbits(w9.x)        | (bfbits(w9.y)        << 16); \
      wa_[9]  = bfbits(w11.x)       | (bfbits(w11.y)       << 16); \
      wa_[10] = bfbits(w12.x)       | (bfbits(w12.y)       << 16); }

// ---------------- fused: logits + online softmax + v-path + projection -------
// R4: register diet to fit 128 VGPR / 4 waves per SIMD with ZERO scratch spill
// (R3: VGPR_Count 84 + ~135 MB of per-iteration spill traffic in WRITE_SIZE).
//  - Gk packed to bf16 pairs (32 -> 16 regs)
//  - angular weights deduped (26 -> 22 regs)
//  - s1,c1 via rsqrt identity; sh,ch via half-angle sqrt (fewer transients)
__global__ __launch_bounds__(256, 4) void fused_kernel(
    const u32* __restrict__ kw2t, const u32* __restrict__ vw2t,
    const float* __restrict__ Wk1, const float* __restrict__ Bk1,
    const float* __restrict__ Gkg, const float* __restrict__ Bkln,
    const float* __restrict__ Wv1, const float* __restrict__ Bv1,
    const float* __restrict__ Gvg, const float* __restrict__ Bvln,
    const float* __restrict__ B2v,
    const bf16* __restrict__ qf, const bf16* __restrict__ P1k, const bf16* __restrict__ P1v,
    const float* __restrict__ pos, const int* __restrict__ seg,
    const int* __restrict__ idx_kj, const int* __restrict__ idx_k,
    const int* __restrict__ row, const int* __restrict__ col,
    float* __restrict__ out, int E)
{
    __shared__ u32 sS[4][16*66];     // per-wave S bf16 pairs: [h][d-pair], stride 66
    int tid = threadIdx.x, lane = tid & 63, wv = tid >> 6;
    int e = __builtin_amdgcn_readfirstlane(blockIdx.x*4 + wv);
    if (e >= E) return;
    int s0 = __builtin_amdgcn_readfirstlane(seg[e]);
    int s1 = __builtin_amdgcn_readfirstlane(seg[e+1]);
    if (s1 <= s0) { out[(size_t)e*128 + lane] = 0.f; out[(size_t)e*128 + 64 + lane] = 0.f; return; }

    float2 b1k = ((const float2*)Bk1)[lane];
    float2 gk  = ((const float2*)Gkg)[lane];
    float2 bk  = ((const float2*)Bkln)[lane];
    float2 b1v = ((const float2*)Bv1)[lane];
    float2 gv  = ((const float2*)Gvg)[lane];
    float2 bv  = ((const float2*)Bvln)[lane];

    int i0 = __builtin_amdgcn_readfirstlane(col[e]);
    int j0 = __builtin_amdgcn_readfirstlane(row[e]);
    float pix = pos[(size_t)i0*3+0], piy = pos[(size_t)i0*3+1], piz = pos[(size_t)i0*3+2];
    float pjx = pos[(size_t)j0*3+0], pjy = pos[(size_t)j0*3+1], pjz = pos[(size_t)j0*3+2];
    float dxx = pix-pjx, dyy = piy-pjy, dzz = piz-pjz;
    float dist = sqrtf(dxx*dxx + dyy*dyy + dzz*dzz);

    EDGE_SETUP(Wk1, b1k, P2ak, P2bk, wak);
    EDGE_SETUP(Wv1, b1v, P2av, P2bv, wav);

    // Gk[h] packed bf16 pair (d0,d1); q and Wk2 are already bf16 so one more
    // rounding here is on par with existing pipeline precision
    u32 Gkp[16];
    {
        const u32* qrow = (const u32*)(qf + (size_t)e*128);
        #pragma unroll
        for (int h = 0; h < 16; ++h) {
            float g0 = 0.f, g1 = 0.f;
            #pragma unroll
            for (int j = 0; j < 4; ++j) {
                u32 qp = qrow[h*4 + j];
                float ql = lo16(qp), qh = hi16(qp);
                u32 w0 = kw2t[(h*8 + 2*j)*64 + lane];
                u32 w1 = kw2t[(h*8 + 2*j + 1)*64 + lane];
                g0 += ql*lo16(w0) + qh*lo16(w1);
                g1 += ql*hi16(w0) + qh*hi16(w1);
            }
            Gkp[h] = bfbits(g0) | (bfbits(g1) << 16);
        }
    }

    float S0[16], S1[16];
    #pragma unroll
    for (int h = 0; h < 16; ++h) { S0[h] = 0.f; S1[h] = 0.f; }
    float m = -1e30f, sden = 0.f;

    const u32* p1ku = (const u32*)P1k;
    const u32* p1vu = (const u32*)P1v;
    float ax = pjx-pix, ay = pjy-piy, az = pjz-piz;

    // software prefetch rotation (indices -> P1 rows -> pos) one triplet ahead
    int kj_p = __builtin_amdgcn_readfirstlane(idx_kj[s0]);
    int kn_p = __builtin_amdgcn_readfirstlane(idx_k[s0]);
    u32 ppk_p = p1ku[(size_t)kj_p*64 + lane];
    u32 ppv_p = p1vu[(size_t)kj_p*64 + lane];
    float pkx = pos[(size_t)kn_p*3+0], pky = pos[(size_t)kn_p*3+1], pkz = pos[(size_t)kn_p*3+2];

    for (int t = s0; t < s1; ++t) {
        u32 ppk = ppk_p, ppv = ppv_p;
        float bx = pkx-pix, by = pky-piy, bz = pkz-piz;
        int tn = (t+1 < s1) ? (t+1) : t;
        kj_p = __builtin_amdgcn_readfirstlane(idx_kj[tn]);
        kn_p = __builtin_amdgcn_readfirstlane(idx_k[tn]);
        ppk_p = p1ku[(size_t)kj_p*64 + lane];
        ppv_p = p1vu[(size_t)kj_p*64 + lane];
        pkx = pos[(size_t)kn_p*3+0]; pky = pos[(size_t)kn_p*3+1]; pkz = pos[(size_t)kn_p*3+2];

        // geometry; sin/cos of ang and ang/2 via algebraic identities (no trig):
        // c1 = cos(atan2(bcr,dt)) = dt/hyp, s1 = bcr/hyp; ang in [0,pi] so
        // sh = sqrt((1-c1)/2), ch = sqrt((1+c1)/2) are both the correct branch.
        float dt = ax*bx + ay*by + az*bz;
        float cx = ay*bz - az*by, cy = az*bx - ax*bz, cz = ax*by - ay*bx;
        float bcr2 = cx*cx + cy*cy + cz*cz;
        float bcr = sqrtf(bcr2);
        float inv_h = rsqrtf(fmaxf(dt*dt + bcr2, 1e-30f));
        float c1a = dt * inv_h;
        float s1a = bcr * inv_h;
        float ang = fast_atan2(bcr, dt);
        float sh  = sqrtf(fmaxf(0.5f*(1.f - c1a), 0.f));
        float ch  = sqrtf(fmaxf(0.5f*(1.f + c1a), 0.f));
        float st3, ct3; __sincosf((1.f/3.f)*ang, &st3, &ct3);
        float s2a = 2.f*s1a*c1a, c2a = 1.f - 2.f*s1a*s1a;
        float s3a = s1a*(3.f - 4.f*s1a*s1a), c3a = c1a*(4.f*c1a*c1a - 3.f);
        float af[11] = {ang, s1a, s2a, s3a, sh, st3, c1a, c2a, c3a, ch, ct3};

        // pre-activations, k-path (A) and v-path (B)
        float v0A = P2ak + lo16(ppk), v1A = P2bk + hi16(ppk);
        float v0B = P2av + lo16(ppv), v1B = P2bv + hi16(ppv);
        #pragma unroll
        for (int f = 0; f < 11; ++f) {
            u32 wkp = wak[f], wvp = wav[f];
            v0A += af[f]*lo16(wkp); v1A += af[f]*hi16(wkp);
            v0B += af[f]*lo16(wvp); v1B += af[f]*hi16(wvp);
        }
        // both LayerNorms, interleaved 7-shfl split reductions
        float sumA = v0A + v1A, ssqA = v0A*v0A + v1A*v1A;
        float sumB = v0B + v1B, ssqB = v0B*v0B + v1B*v1B;
        float rA = ((lane&1) ? ssqA : sumA) + __shfl_xor((lane&1) ? sumA : ssqA, 1, 64);
        float rB = ((lane&1) ? ssqB : sumB) + __shfl_xor((lane&1) ? sumB : ssqB, 1, 64);
        rA += __shfl_xor(rA, 2, 64);  rB += __shfl_xor(rB, 2, 64);
        rA += __shfl_xor(rA, 4, 64);  rB += __shfl_xor(rB, 4, 64);
        rA += __shfl_xor(rA, 8, 64);  rB += __shfl_xor(rB, 8, 64);
        rA += __shfl_xor(rA, 16, 64); rB += __shfl_xor(rB, 16, 64);
        rA += __shfl_xor(rA, 32, 64); rB += __shfl_xor(rB, 32, 64);
        float oA = __shfl_xor(rA, 1, 64), oB = __shfl_xor(rB, 1, 64);
        float totA  = (lane&1) ? oA : rA, tot2A = (lane&1) ? rA : oA;
        float totB  = (lane&1) ? oB : rB, tot2B = (lane&1) ? rB : oB;
        float muA = totA * (1.f/128.f);
        float muB = totB * (1.f/128.f);
        float varA = fmaxf(tot2A * (1.f/128.f) - muA*muA, 0.f);
        float varB = fmaxf(tot2B * (1.f/128.f) - muB*muB, 0.f);
        float rsA = rsqrtf(varA + 1e-5f), rsB = rsqrtf(varB + 1e-5f);
        float h0A = fmaxf(gk.x*(v0A-muA)*rsA + bk.x, 0.f);
        float h1A = fmaxf(gk.y*(v1A-muA)*rsA + bk.y, 0.f);
        float h0B = fmaxf(gv.x*(v0B-muB)*rsB + bv.x, 0.f);
        float h1B = fmaxf(gv.y*(v1B-muB)*rsB + bv.y, 0.f);

        // logits: per-head partials then 17-shfl split-exchange butterfly
        float p[16];
        #pragma unroll
        for (int h = 0; h < 16; ++h) {
            u32 g = Gkp[h];
            p[h] = h0A*lo16(g) + h1A*hi16(g);
        }
        float a8[8];
        { int up = lane & 1;
          #pragma unroll
          for (int i = 0; i < 8; ++i) {
            float kp = up ? p[i+8] : p[i];
            float sd = up ? p[i]   : p[i+8];
            a8[i] = kp + __shfl_xor(sd, 1, 64);
          } }
        float a4[4];
        { int up = lane & 2;
          #pragma unroll
          for (int i = 0; i < 4; ++i) {
            float kp = up ? a8[i+4] : a8[i];
            float sd = up ? a8[i]   : a8[i+4];
            a4[i] = kp + __shfl_xor(sd, 2, 64);
          } }
        float a2[2];
        { int up = lane & 4;
          #pragma unroll
          for (int i = 0; i < 2; ++i) {
            float kp = up ? a4[i+2] : a4[i];
            float sd = up ? a4[i]   : a4[i+2];
            a2[i] = kp + __shfl_xor(sd, 4, 64);
          } }
        float a1;
        { int up = lane & 8;
          float kp = up ? a2[1] : a2[0];
          float sd = up ? a2[0] : a2[1];
          a1 = kp + __shfl_xor(sd, 8, 64);
        }
        a1 += __shfl_xor(a1, 16, 64);
        a1 += __shfl_xor(a1, 32, 64);
        float lg = a1 * RSQRT8;      // lane l: logit for head PERM4(l&15)

        // online softmax with defer-max (rescale only when max grows > 8)
        if (__any(lg > m + 8.f)) {
            float nm = fmaxf(m, lg);
            float fac = __expf(m - nm);
            sden *= fac; m = nm;
            #pragma unroll
            for (int h = 0; h < 16; ++h) {
                float fh = __shfl(fac, PERM4(h), 64);
                S0[h] *= fh; S1[h] *= fh;
            }
        }
        float ex = __expf(lg - m);
        sden += ex;
        #pragma unroll
        for (int h = 0; h < 16; ++h) {
            float alh = __shfl(ex, PERM4(h), 64);
            S0[h] += alh*h0B; S1[h] += alh*h1B;
        }
    }

    // normalize by softmax denominator while staging S as bf16 pairs
    float inv = 1.f / sden;
    #pragma unroll
    for (int h = 0; h < 16; ++h) {
        float sc = __shfl(inv, PERM4(h), 64);
        sS[wv][h*66 + lane] = bfbits(S0[h]*sc) | (bfbits(S1[h]*sc) << 16);
    }
    __threadfence_block();
    // projection: out[o] = sum_d S[o>>3][d]*Wv2[d][o] + b2[o];  o0=lane, o1=lane+64
    int h0i = lane >> 3, h1i = 8 + (lane >> 3);
    float acc0 = B2v[lane], acc1 = B2v[lane + 64];
    const u32* sr0 = &sS[wv][h0i*66];
    const u32* sr1 = &sS[wv][h1i*66];
    #pragma unroll 8
    for (int j = 0; j < 64; ++j) {
        u32 us0 = sr0[j], uw0 = vw2t[j*128 + lane];
        u32 us1 = sr1[j], uw1 = vw2t[j*128 + 64 + lane];
        acc0 += lo16(us0)*lo16(uw0) + hi16(us0)*hi16(uw0);
        acc1 += lo16(us1)*lo16(uw1) + hi16(us1)*hi16(uw1);
    }
    out[(size_t)e*128 + lane] = acc0;
    out[(size_t)e*128 + 64 + lane] = acc1;
}

extern "C" void kernel_launch(void* const* d_in, const int* in_sizes, int n_in,
                              void* d_out, int out_size, void* d_ws, size_t ws_size,
                              hipStream_t stream)
{
    const float* h_bond = (const float*)d_in[1];
    const float* pos    = (const float*)d_in[2];
    const float* hkW1 = (const float*)d_in[3];
    const float* hkb1 = (const float*)d_in[4];
    const float* hkg  = (const float*)d_in[5];
    const float* hkb  = (const float*)d_in[6];
    const float* hkW2 = (const float*)d_in[7];
    const float* hvW1 = (const float*)d_in[9];
    const float* hvb1 = (const float*)d_in[10];
    const float* hvg  = (const float*)d_in[11];
    const float* hvb  = (const float*)d_in[12];
    const float* hvW2 = (const float*)d_in[13];
    const float* hvb2 = (const float*)d_in[14];
    const float* hqW1 = (const float*)d_in[15];
    const float* hqb1 = (const float*)d_in[16];
    const float* hqg  = (const float*)d_in[17];
    const float* hqb  = (const float*)d_in[18];
    const float* hqW2 = (const float*)d_in[19];
    const float* hqb2 = (const float*)d_in[20];
    const int* row    = (const int*)d_in[21];
    const int* col    = (const int*)d_in[22];
    const int* idx_k  = (const int*)d_in[25];
    const int* idx_kj = (const int*)d_in[26];
    const int* idx_ji = (const int*)d_in[27];

    int E = in_sizes[21];
    int T = in_sizes[27];

    char* w = (char*)d_ws;
    size_t off = 0;
    auto carve = [&](size_t bytes) -> void* {
        void* p = w + off;
        off = (off + bytes + 255) & ~(size_t)255;
        return p;
    };
    int*  seg   = (int*) carve(((size_t)E + 1) * sizeof(int));
    bf16* qf    = (bf16*)carve((size_t)E * 128 * sizeof(bf16));
    bf16* P1k   = (bf16*)carve((size_t)E * 128 * sizeof(bf16));
    bf16* P1v   = (bf16*)carve((size_t)E * 128 * sizeof(bf16));
    u32*  kw2t  = (u32*) carve(8192 * sizeof(u32));
    u32*  vw2t  = (u32*) carve(8192 * sizeof(u32));

    if (off > ws_size) {
        marker_kernel<<<(out_size + 255)/256, 256, 0, stream>>>((float*)d_out, out_size);
        return;
    }

    int gq = (E + 15)/16;
    int gw = (E + 3)/4;
    seg_start_kernel<<<(E + 1 + 255)/256, 256, 0, stream>>>(idx_ji, T, seg, E);
    pack_w2<<<32, 256, 0, stream>>>(hkW2, hvW2, kw2t, vw2t);
    q_kernel<<<gq, 128, 0, stream>>>(hqW1, hqb1, hqg, hqb, hqW2, hqb2, h_bond, qf, E);
    p_prep<<<gq, 128, 0, stream>>>(hkW1, h_bond, pos, row, col, P1k, E);
    p_prep<<<gq, 128, 0, stream>>>(hvW1, h_bond, pos, row, col, P1v, E);
    fused_kernel<<<gw, 256, 0, stream>>>(kw2t, vw2t,
        hkW1, hkb1, hkg, hkb,
        hvW1, hvb1, hvg, hvb,
        hvb2, qf, P1k, P1v, pos, seg, idx_kj, idx_k, row, col, (float*)d_out, E);
}

// Round 5
// 2087.757 us; speedup vs baseline: 1.4669x; 1.4669x over previous
//
#include <hip/hip_runtime.h>
#include <hip/hip_bf16.h>
#include <math.h>

typedef __hip_bfloat16 bf16;
typedef unsigned int u32;

__device__ __forceinline__ float b2f(bf16 x){ return __bfloat162float(x); }
__device__ __forceinline__ bf16  f2b(float x){ return __float2bfloat16(x); }
__device__ __forceinline__ float lo16(u32 u){ return __uint_as_float(u << 16); }
__device__ __forceinline__ float hi16(u32 u){ return __uint_as_float(u & 0xFFFF0000u); }
// float -> bf16 bits with round-to-nearest-even
__device__ __forceinline__ u32 bfbits(float x){
    u32 u = __float_as_uint(x);
    return (u + 0x7FFFu + ((u >> 16) & 1u)) >> 16;
}

#define RSQRT8 0.35355339059327373f
#define G_STEP (10.0f/19.0f)
#define G_COEF (-0.5f/(G_STEP*G_STEP))

// butterfly layout involution: lane l holds head PERM4(l&15); PERM4 is self-inverse
__device__ __forceinline__ constexpr int PERM4(int h){
    return ((h&1)<<3) | ((h&2)<<1) | ((h&4)>>1) | ((h&8)>>3);
}

// fast atan2 for y >= 0 (result in [0, pi]); poly max err ~1.6e-6 rad
__device__ __forceinline__ float fast_atan2(float y, float x){
    float ax = fabsf(x);
    float mn = fminf(y, ax), mx = fmaxf(y, ax);
    float t = mn / fmaxf(mx, 1e-30f);
    float s = t*t;
    float p = t * (0.99997726f + s*(-0.33262347f + s*(0.19354346f +
              s*(-0.11643287f + s*(0.05265332f + s*(-0.01172120f))))));
    float r = (y > ax) ? (1.5707963267948966f - p) : p;
    r = (x < 0.f) ? (3.14159265358979323f - r) : r;
    return r;
}

// inputs are PROVEN f32 (R1/R2 bf16 interpretation -> NaN; R3/R4 probe-selected f32 -> pass)

// ---------------- seg starts (idx_ji sorted) ----------------
__global__ void seg_start_kernel(const int* __restrict__ idx_ji, int T,
                                 int* __restrict__ seg, int E)
{
    int e = blockIdx.x * blockDim.x + threadIdx.x;
    if (e > E) return;
    int lo = 0, hi = T;
    while (lo < hi) { int mid = (lo + hi) >> 1; if (idx_ji[mid] < e) lo = mid + 1; else hi = mid; }
    seg[e] = lo;
}

__global__ void marker_kernel(float* out, int n){
    int i = blockIdx.x * blockDim.x + threadIdx.x;
    if (i < n) out[i] = 12345.0f;
}

// ---------------- pack W2 matrices to bf16-pair layouts (L2-resident) --------
// kw2t[c*64 + p]  = (Wk2[2p][c],  Wk2[2p+1][c])   (Gk compute: lane = p)
// vw2t[j*128 + o] = (Wv2[2j][o],  Wv2[2j+1][o])   (projection: lane = o)
__global__ void pack_w2(const float* __restrict__ Wk2, const float* __restrict__ Wv2,
                        u32* __restrict__ kw2t, u32* __restrict__ vw2t)
{
    int idx = blockIdx.x*256 + threadIdx.x;
    if (idx >= 8192) return;
    int c = idx >> 6, p = idx & 63;
    kw2t[idx] = bfbits(Wk2[(size_t)(2*p)*128 + c]) | (bfbits(Wk2[(size_t)(2*p+1)*128 + c]) << 16);
    int j = idx >> 7, o = idx & 127;
    vw2t[idx] = bfbits(Wv2[(size_t)(2*j)*128 + o]) | (bfbits(Wv2[(size_t)(2*j+1)*128 + o]) << 16);
}

// ---------------- q = MLP_hq(h_bond) per edge -> bf16, 4-edge batched --------
__global__ __launch_bounds__(128) void q_kernel(
    const float* __restrict__ W1, const float* __restrict__ B1,
    const float* __restrict__ G,  const float* __restrict__ Bln,
    const float* __restrict__ W2, const float* __restrict__ B2,
    const float* __restrict__ h_bond, bf16* __restrict__ qout, int E)
{
    __shared__ u32 sW[128*65];       // [dim][row-pair] packed bf16, row stride 130 bf16
    __shared__ float sH[16][130];
    __shared__ float sX[4][130];
    __shared__ float sRed[4][4];
    int tid = threadIdx.x; int wv = tid>>6, lane = tid&63;
    int base = blockIdx.x * 16;

    for (int idx = tid; idx < 128*128; idx += 128) {
        int i = idx >> 7, d = idx & 127;
        ((bf16*)sW)[d*130 + i] = f2b(W1[idx]);
    }
    __syncthreads();
    for (int e4 = 0; e4 < 16; e4 += 4) {
        #pragma unroll
        for (int q = 0; q < 4; ++q) {
            int e = base + e4 + q;
            sX[q][tid] = (e < E) ? h_bond[(size_t)e*128 + tid] : 0.f;
        }
        __syncthreads();
        float b1t = B1[tid];
        float ac[4] = {b1t, b1t, b1t, b1t};
        const u32* wrow = &sW[tid*65];
        #pragma unroll 4
        for (int j = 0; j < 64; ++j) {
            u32 w = wrow[j]; float wl = lo16(w), wh = hi16(w);
            #pragma unroll
            for (int q = 0; q < 4; ++q)
                ac[q] += sX[q][2*j]*wl + sX[q][2*j+1]*wh;
        }
        // 4 interleaved (sum, sumsq) wave reductions
        float s1v[4], s2v[4];
        #pragma unroll
        for (int q = 0; q < 4; ++q) { s1v[q] = ac[q]; s2v[q] = ac[q]*ac[q]; }
        #pragma unroll
        for (int m = 1; m < 64; m <<= 1) {
            #pragma unroll
            for (int q = 0; q < 4; ++q) {
                s1v[q] += __shfl_xor(s1v[q], m, 64);
                s2v[q] += __shfl_xor(s2v[q], m, 64);
            }
        }
        if (lane == 0) {
            #pragma unroll
            for (int q = 0; q < 4; ++q) { sRed[q][wv*2] = s1v[q]; sRed[q][wv*2+1] = s2v[q]; }
        }
        __syncthreads();
        float gt = G[tid], bt = Bln[tid];
        #pragma unroll
        for (int q = 0; q < 4; ++q) {
            float tot = sRed[q][0] + sRed[q][2], tot2 = sRed[q][1] + sRed[q][3];
            float mu = tot * (1.f/128.f);
            float var = fmaxf(tot2 * (1.f/128.f) - mu*mu, 0.f);
            float nv = gt * (ac[q] - mu) * rsqrtf(var + 1e-5f) + bt;
            sH[e4+q][tid] = fmaxf(nv, 0.f);
        }
        __syncthreads();
    }
    for (int idx = tid; idx < 128*128; idx += 128) {
        int i = idx >> 7, d = idx & 127;
        ((bf16*)sW)[d*130 + i] = f2b(W2[idx]);
    }
    __syncthreads();
    for (int e4 = 0; e4 < 16; e4 += 4) {
        float b2t = B2[tid];
        float ac[4] = {b2t, b2t, b2t, b2t};
        const u32* wrow = &sW[tid*65];
        #pragma unroll 4
        for (int j = 0; j < 64; ++j) {
            u32 w = wrow[j]; float wl = lo16(w), wh = hi16(w);
            #pragma unroll
            for (int q = 0; q < 4; ++q)
                ac[q] += sH[e4+q][2*j]*wl + sH[e4+q][2*j+1]*wh;
        }
        #pragma unroll
        for (int q = 0; q < 4; ++q) {
            int e = base + e4 + q;
            if (e < E) qout[(size_t)e*128 + tid] = f2b(ac[q]);
        }
    }
}

// ---------------- P1[e] = h_bond[e]@W1[0:128] + rfeat[e]@W1[128:148] -> bf16 --
// 4-edge batched: weight ds_reads amortized x4, 2 barriers per 4 edges, 4 indep FMA chains
__global__ __launch_bounds__(128) void p_prep(
    const float* __restrict__ W1, const float* __restrict__ h_bond,
    const float* __restrict__ pos, const int* __restrict__ row,
    const int* __restrict__ col, bf16* __restrict__ P1, int E)
{
    __shared__ u32 sW[128*75];       // [dim][row-pair], 148 rows -> 74 pairs, stride 150 bf16
    __shared__ float sX[4][152];
    int tid = threadIdx.x;
    for (int idx = tid; idx < 148*128; idx += 128) {
        int i = idx >> 7, d = idx & 127;
        ((bf16*)sW)[d*150 + i] = f2b(W1[idx]);
    }
    __syncthreads();
    int base = blockIdx.x * 16;
    for (int e4 = 0; e4 < 16; e4 += 4) {
        #pragma unroll
        for (int q = 0; q < 4; ++q) {
            int e = base + e4 + q;
            sX[q][tid] = (e < E) ? h_bond[(size_t)e*128 + tid] : 0.f;
        }
        if (tid < 80) {
            int q = tid / 20, g = tid % 20;
            int e = base + e4 + q;
            float rf = 0.f;
            if (e < E) {
                int i0 = col[e], j0 = row[e];
                float dx = pos[(size_t)i0*3+0] - pos[(size_t)j0*3+0];
                float dy = pos[(size_t)i0*3+1] - pos[(size_t)j0*3+1];
                float dz = pos[(size_t)i0*3+2] - pos[(size_t)j0*3+2];
                float dist = sqrtf(dx*dx + dy*dy + dz*dz);
                float t = dist - (float)g * G_STEP;
                rf = __expf(G_COEF * t * t);
            }
            sX[q][128 + g] = rf;
        }
        __syncthreads();
        float acc0 = 0.f, acc1 = 0.f, acc2 = 0.f, acc3 = 0.f;
        const u32* wrow = &sW[tid*75];
        #pragma unroll 4
        for (int j = 0; j < 74; ++j) {
            u32 w = wrow[j]; float wl = lo16(w), wh = hi16(w);
            acc0 += sX[0][2*j]*wl + sX[0][2*j+1]*wh;
            acc1 += sX[1][2*j]*wl + sX[1][2*j+1]*wh;
            acc2 += sX[2][2*j]*wl + sX[2][2*j+1]*wh;
            acc3 += sX[3][2*j]*wl + sX[3][2*j+1]*wh;
        }
        int e = base + e4;
        if (e   < E) P1[(size_t)e*128     + tid] = f2b(acc0);
        if (e+1 < E) P1[(size_t)(e+1)*128 + tid] = f2b(acc1);
        if (e+2 < E) P1[(size_t)(e+2)*128 + tid] = f2b(acc2);
        if (e+3 < E) P1[(size_t)(e+3)*128 + tid] = f2b(acc3);
        __syncthreads();
    }
}

// per-edge P2 pre-act (gaussian part + b1); angular weights now live in LDS
#define EDGE_P2(W1full, b1v_, P2a_, P2b_) \
    float P2a_ = b1v_.x, P2b_ = b1v_.y; \
    { const float2* wbp = (const float2*)((W1full) + (size_t)148*128); \
      for (int g2 = 0; g2 < 20; ++g2) { \
        float tg = dist - (float)g2 * G_STEP; \
        float rf = __expf(G_COEF * tg * tg); \
        float2 wb = wbp[g2*64 + lane]; \
        P2a_ += rf * wb.x; \
        P2b_ += rf * wb.y; \
      } }

// ---------------- fused: logits + online softmax + v-path + projection -------
// R5: live-register diet WITHOUT spill-inducing occupancy hints.
//  - R4 lesson: __launch_bounds__ min-occupancy made the allocator spill-chase
//    (64 VGPR + 5.3 GB scratch traffic). Now: waves_per_eu(2,4) = no forced
//    spill (min 2 -> 256-reg cap), allocator free up to 128 regs (max 4).
//  - angular weight pairs (block-invariant!) moved regs -> shared LDS: -22 regs,
//    +22 conflict-free stride-1 ds_read_b32 per triplet (R1-proven pattern).
__global__ __launch_bounds__(256)
__attribute__((amdgpu_waves_per_eu(2, 4)))
void fused_kernel(
    const u32* __restrict__ kw2t, const u32* __restrict__ vw2t,
    const float* __restrict__ Wk1, const float* __restrict__ Bk1,
    const float* __restrict__ Gkg, const float* __restrict__ Bkln,
    const float* __restrict__ Wv1, const float* __restrict__ Bv1,
    const float* __restrict__ Gvg, const float* __restrict__ Bvln,
    const float* __restrict__ B2v,
    const bf16* __restrict__ qf, const bf16* __restrict__ P1k, const bf16* __restrict__ P1v,
    const float* __restrict__ pos, const int* __restrict__ seg,
    const int* __restrict__ idx_kj, const int* __restrict__ idx_k,
    const int* __restrict__ row, const int* __restrict__ col,
    float* __restrict__ out, int E)
{
    __shared__ u32 sS[4][16*66];     // per-wave S bf16 pairs: [h][d-pair], stride 66
    __shared__ u32 sWA[2][11*64];    // deduped angular weight pairs: [path][f][lane]
    int tid = threadIdx.x, lane = tid & 63, wv = tid >> 6;

    // block-cooperative populate of sWA (weights are edge-independent).
    // Feature order: {ang, s1, s2, s3, sh, st3, c1, c2, c3, ch, ct3};
    // original 13 feats have s1 at {1,4}, c1 at {7,10} -> fold weight pairs.
    if (tid < 128) {
        int path = tid >> 6, l = tid & 63;
        const float* W1full = path ? Wv1 : Wk1;
        const float2* wap = (const float2*)(W1full + (size_t)168*128);
        float2 w0  = wap[ 0*64 + l];
        float2 w1  = wap[ 1*64 + l];
        float2 w2  = wap[ 2*64 + l];
        float2 w3  = wap[ 3*64 + l];
        float2 w4  = wap[ 4*64 + l];
        float2 w5  = wap[ 5*64 + l];
        float2 w6  = wap[ 6*64 + l];
        float2 w7  = wap[ 7*64 + l];
        float2 w8  = wap[ 8*64 + l];
        float2 w9  = wap[ 9*64 + l];
        float2 w10 = wap[10*64 + l];
        float2 w11 = wap[11*64 + l];
        float2 w12 = wap[12*64 + l];
        u32* dst = &sWA[path][0];
        dst[ 0*64 + l] = bfbits(w0.x)       | (bfbits(w0.y)       << 16);
        dst[ 1*64 + l] = bfbits(w1.x+w4.x)  | (bfbits(w1.y+w4.y)  << 16);
        dst[ 2*64 + l] = bfbits(w2.x)       | (bfbits(w2.y)       << 16);
        dst[ 3*64 + l] = bfbits(w3.x)       | (bfbits(w3.y)       << 16);
        dst[ 4*64 + l] = bfbits(w5.x)       | (bfbits(w5.y)       << 16);
        dst[ 5*64 + l] = bfbits(w6.x)       | (bfbits(w6.y)       << 16);
        dst[ 6*64 + l] = bfbits(w7.x+w10.x) | (bfbits(w7.y+w10.y) << 16);
        dst[ 7*64 + l] = bfbits(w8.x)       | (bfbits(w8.y)       << 16);
        dst[ 8*64 + l] = bfbits(w9.x)       | (bfbits(w9.y)       << 16);
        dst[ 9*64 + l] = bfbits(w11.x)      | (bfbits(w11.y)      << 16);
        dst[10*64 + l] = bfbits(w12.x)      | (bfbits(w12.y)      << 16);
    }
    __syncthreads();                 // ONLY barrier; before any divergent return

    int e = __builtin_amdgcn_readfirstlane(blockIdx.x*4 + wv);
    if (e >= E) return;
    int s0 = __builtin_amdgcn_readfirstlane(seg[e]);
    int s1 = __builtin_amdgcn_readfirstlane(seg[e+1]);
    if (s1 <= s0) { out[(size_t)e*128 + lane] = 0.f; out[(size_t)e*128 + 64 + lane] = 0.f; return; }

    float2 b1k = ((const float2*)Bk1)[lane];
    float2 gk  = ((const float2*)Gkg)[lane];
    float2 bk  = ((const float2*)Bkln)[lane];
    float2 b1v = ((const float2*)Bv1)[lane];
    float2 gv  = ((const float2*)Gvg)[lane];
    float2 bv  = ((const float2*)Bvln)[lane];

    int i0 = __builtin_amdgcn_readfirstlane(col[e]);
    int j0 = __builtin_amdgcn_readfirstlane(row[e]);
    float pix = pos[(size_t)i0*3+0], piy = pos[(size_t)i0*3+1], piz = pos[(size_t)i0*3+2];
    float pjx = pos[(size_t)j0*3+0], pjy = pos[(size_t)j0*3+1], pjz = pos[(size_t)j0*3+2];
    float dxx = pix-pjx, dyy = piy-pjy, dzz = piz-pjz;
    float dist = sqrtf(dxx*dxx + dyy*dyy + dzz*dzz);

    EDGE_P2(Wk1, b1k, P2ak, P2bk);
    EDGE_P2(Wv1, b1v, P2av, P2bv);

    // Gk[h] packed bf16 pair (d0,d1)
    u32 Gkp[16];
    {
        const u32* qrow = (const u32*)(qf + (size_t)e*128);
        #pragma unroll
        for (int h = 0; h < 16; ++h) {
            float g0 = 0.f, g1 = 0.f;
            #pragma unroll
            for (int j = 0; j < 4; ++j) {
                u32 qp = qrow[h*4 + j];
                float ql = lo16(qp), qh = hi16(qp);
                u32 w0 = kw2t[(h*8 + 2*j)*64 + lane];
                u32 w1 = kw2t[(h*8 + 2*j + 1)*64 + lane];
                g0 += ql*lo16(w0) + qh*lo16(w1);
                g1 += ql*hi16(w0) + qh*hi16(w1);
            }
            Gkp[h] = bfbits(g0) | (bfbits(g1) << 16);
        }
    }

    float S0[16], S1[16];
    #pragma unroll
    for (int h = 0; h < 16; ++h) { S0[h] = 0.f; S1[h] = 0.f; }
    float m = -1e30f, sden = 0.f;

    const u32* p1ku = (const u32*)P1k;
    const u32* p1vu = (const u32*)P1v;
    float ax = pjx-pix, ay = pjy-piy, az = pjz-piz;

    // software prefetch rotation (indices -> P1 rows -> pos) one triplet ahead
    int kj_p = __builtin_amdgcn_readfirstlane(idx_kj[s0]);
    int kn_p = __builtin_amdgcn_readfirstlane(idx_k[s0]);
    u32 ppk_p = p1ku[(size_t)kj_p*64 + lane];
    u32 ppv_p = p1vu[(size_t)kj_p*64 + lane];
    float pkx = pos[(size_t)kn_p*3+0], pky = pos[(size_t)kn_p*3+1], pkz = pos[(size_t)kn_p*3+2];

    for (int t = s0; t < s1; ++t) {
        u32 ppk = ppk_p, ppv = ppv_p;
        float bx = pkx-pix, by = pky-piy, bz = pkz-piz;
        int tn = (t+1 < s1) ? (t+1) : t;
        kj_p = __builtin_amdgcn_readfirstlane(idx_kj[tn]);
        kn_p = __builtin_amdgcn_readfirstlane(idx_k[tn]);
        ppk_p = p1ku[(size_t)kj_p*64 + lane];
        ppv_p = p1vu[(size_t)kj_p*64 + lane];
        pkx = pos[(size_t)kn_p*3+0]; pky = pos[(size_t)kn_p*3+1]; pkz = pos[(size_t)kn_p*3+2];

        // geometry; s1,c1 via rsqrt identity; sh,ch via half-angle (ang in [0,pi])
        float dt = ax*bx + ay*by + az*bz;
        float cx = ay*bz - az*by, cy = az*bx - ax*bz, cz = ax*by - ay*bx;
        float bcr2 = cx*cx + cy*cy + cz*cz;
        float bcr = sqrtf(bcr2);
        float inv_h = rsqrtf(fmaxf(dt*dt + bcr2, 1e-30f));
        float c1a = dt * inv_h;
        float s1a = bcr * inv_h;
        float ang = fast_atan2(bcr, dt);
        float sh  = sqrtf(fmaxf(0.5f*(1.f - c1a), 0.f));
        float ch  = sqrtf(fmaxf(0.5f*(1.f + c1a), 0.f));
        float st3, ct3; __sincosf((1.f/3.f)*ang, &st3, &ct3);
        float s2a = 2.f*s1a*c1a, c2a = 1.f - 2.f*s1a*s1a;
        float s3a = s1a*(3.f - 4.f*s1a*s1a), c3a = c1a*(4.f*c1a*c1a - 3.f);
        float af[11] = {ang, s1a, s2a, s3a, sh, st3, c1a, c2a, c3a, ch, ct3};

        // pre-activations, k-path (A) and v-path (B); weights from LDS
        float v0A = P2ak + lo16(ppk), v1A = P2bk + hi16(ppk);
        float v0B = P2av + lo16(ppv), v1B = P2bv + hi16(ppv);
        #pragma unroll
        for (int f = 0; f < 11; ++f) {
            u32 wkp = sWA[0][f*64 + lane];
            u32 wvp = sWA[1][f*64 + lane];
            v0A += af[f]*lo16(wkp); v1A += af[f]*hi16(wkp);
            v0B += af[f]*lo16(wvp); v1B += af[f]*hi16(wvp);
        }
        // both LayerNorms, interleaved 7-shfl split reductions
        float sumA = v0A + v1A, ssqA = v0A*v0A + v1A*v1A;
        float sumB = v0B + v1B, ssqB = v0B*v0B + v1B*v1B;
        float rA = ((lane&1) ? ssqA : sumA) + __shfl_xor((lane&1) ? sumA : ssqA, 1, 64);
        float rB = ((lane&1) ? ssqB : sumB) + __shfl_xor((lane&1) ? sumB : ssqB, 1, 64);
        rA += __shfl_xor(rA, 2, 64);  rB += __shfl_xor(rB, 2, 64);
        rA += __shfl_xor(rA, 4, 64);  rB += __shfl_xor(rB, 4, 64);
        rA += __shfl_xor(rA, 8, 64);  rB += __shfl_xor(rB, 8, 64);
        rA += __shfl_xor(rA, 16, 64); rB += __shfl_xor(rB, 16, 64);
        rA += __shfl_xor(rA, 32, 64); rB += __shfl_xor(rB, 32, 64);
        float oA = __shfl_xor(rA, 1, 64), oB = __shfl_xor(rB, 1, 64);
        float totA  = (lane&1) ? oA : rA, tot2A = (lane&1) ? rA : oA;
        float totB  = (lane&1) ? oB : rB, tot2B = (lane&1) ? rB : oB;
        float muA = totA * (1.f/128.f);
        float muB = totB * (1.f/128.f);
        float varA = fmaxf(tot2A * (1.f/128.f) - muA*muA, 0.f);
        float varB = fmaxf(tot2B * (1.f/128.f) - muB*muB, 0.f);
        float rsA = rsqrtf(varA + 1e-5f), rsB = rsqrtf(varB + 1e-5f);
        float h0A = fmaxf(gk.x*(v0A-muA)*rsA + bk.x, 0.f);
        float h1A = fmaxf(gk.y*(v1A-muA)*rsA + bk.y, 0.f);
        float h0B = fmaxf(gv.x*(v0B-muB)*rsB + bv.x, 0.f);
        float h1B = fmaxf(gv.y*(v1B-muB)*rsB + bv.y, 0.f);

        // logits: per-head partials then 17-shfl split-exchange butterfly
        float p[16];
        #pragma unroll
        for (int h = 0; h < 16; ++h) {
            u32 g = Gkp[h];
            p[h] = h0A*lo16(g) + h1A*hi16(g);
        }
        float a8[8];
        { int up = lane & 1;
          #pragma unroll
          for (int i = 0; i < 8; ++i) {
            float kp = up ? p[i+8] : p[i];
            float sd = up ? p[i]   : p[i+8];
            a8[i] = kp + __shfl_xor(sd, 1, 64);
          } }
        float a4[4];
        { int up = lane & 2;
          #pragma unroll
          for (int i = 0; i < 4; ++i) {
            float kp = up ? a8[i+4] : a8[i];
            float sd = up ? a8[i]   : a8[i+4];
            a4[i] = kp + __shfl_xor(sd, 2, 64);
          } }
        float a2[2];
        { int up = lane & 4;
          #pragma unroll
          for (int i = 0; i < 2; ++i) {
            float kp = up ? a4[i+2] : a4[i];
            float sd = up ? a4[i]   : a4[i+2];
            a2[i] = kp + __shfl_xor(sd, 4, 64);
          } }
        float a1;
        { int up = lane & 8;
          float kp = up ? a2[1] : a2[0];
          float sd = up ? a2[0] : a2[1];
          a1 = kp + __shfl_xor(sd, 8, 64);
        }
        a1 += __shfl_xor(a1, 16, 64);
        a1 += __shfl_xor(a1, 32, 64);
        float lg = a1 * RSQRT8;      // lane l: logit for head PERM4(l&15)

        // online softmax with defer-max (rescale only when max grows > 8)
        if (__any(lg > m + 8.f)) {
            float nm = fmaxf(m, lg);
            float fac = __expf(m - nm);
            sden *= fac; m = nm;
            #pragma unroll
            for (int h = 0; h < 16; ++h) {
                float fh = __shfl(fac, PERM4(h), 64);
                S0[h] *= fh; S1[h] *= fh;
            }
        }
        float ex = __expf(lg - m);
        sden += ex;
        #pragma unroll
        for (int h = 0; h < 16; ++h) {
            float alh = __shfl(ex, PERM4(h), 64);
            S0[h] += alh*h0B; S1[h] += alh*h1B;
        }
    }

    // normalize by softmax denominator while staging S as bf16 pairs
    float inv = 1.f / sden;
    #pragma unroll
    for (int h = 0; h < 16; ++h) {
        float sc = __shfl(inv, PERM4(h), 64);
        sS[wv][h*66 + lane] = bfbits(S0[h]*sc) | (bfbits(S1[h]*sc) << 16);
    }
    __threadfence_block();
    // projection: out[o] = sum_d S[o>>3][d]*Wv2[d][o] + b2[o];  o0=lane, o1=lane+64
    int h0i = lane >> 3, h1i = 8 + (lane >> 3);
    float acc0 = B2v[lane], acc1 = B2v[lane + 64];
    const u32* sr0 = &sS[wv][h0i*66];
    const u32* sr1 = &sS[wv][h1i*66];
    #pragma unroll 8
    for (int j = 0; j < 64; ++j) {
        u32 us0 = sr0[j], uw0 = vw2t[j*128 + lane];
        u32 us1 = sr1[j], uw1 = vw2t[j*128 + 64 + lane];
        acc0 += lo16(us0)*lo16(uw0) + hi16(us0)*hi16(uw0);
        acc1 += lo16(us1)*lo16(uw1) + hi16(us1)*hi16(uw1);
    }
    out[(size_t)e*128 + lane] = acc0;
    out[(size_t)e*128 + 64 + lane] = acc1;
}

extern "C" void kernel_launch(void* const* d_in, const int* in_sizes, int n_in,
                              void* d_out, int out_size, void* d_ws, size_t ws_size,
                              hipStream_t stream)
{
    const float* h_bond = (const float*)d_in[1];
    const float* pos    = (const float*)d_in[2];
    const float* hkW1 = (const float*)d_in[3];
    const float* hkb1 = (const float*)d_in[4];
    const float* hkg  = (const float*)d_in[5];
    const float* hkb  = (const float*)d_in[6];
    const float* hkW2 = (const float*)d_in[7];
    const float* hvW1 = (const float*)d_in[9];
    const float* hvb1 = (const float*)d_in[10];
    const float* hvg  = (const float*)d_in[11];
    const float* hvb  = (const float*)d_in[12];
    const float* hvW2 = (const float*)d_in[13];
    const float* hvb2 = (const float*)d_in[14];
    const float* hqW1 = (const float*)d_in[15];
    const float* hqb1 = (const float*)d_in[16];
    const float* hqg  = (const float*)d_in[17];
    const float* hqb  = (const float*)d_in[18];
    const float* hqW2 = (const float*)d_in[19];
    const float* hqb2 = (const float*)d_in[20];
    const int* row    = (const int*)d_in[21];
    const int* col    = (const int*)d_in[22];
    const int* idx_k  = (const int*)d_in[25];
    const int* idx_kj = (const int*)d_in[26];
    const int* idx_ji = (const int*)d_in[27];

    int E = in_sizes[21];
    int T = in_sizes[27];

    char* w = (char*)d_ws;
    size_t off = 0;
    auto carve = [&](size_t bytes) -> void* {
        void* p = w + off;
        off = (off + bytes + 255) & ~(size_t)255;
        return p;
    };
    int*  seg   = (int*) carve(((size_t)E + 1) * sizeof(int));
    bf16* qf    = (bf16*)carve((size_t)E * 128 * sizeof(bf16));
    bf16* P1k   = (bf16*)carve((size_t)E * 128 * sizeof(bf16));
    bf16* P1v   = (bf16*)carve((size_t)E * 128 * sizeof(bf16));
    u32*  kw2t  = (u32*) carve(8192 * sizeof(u32));
    u32*  vw2t  = (u32*) carve(8192 * sizeof(u32));

    if (off > ws_size) {
        marker_kernel<<<(out_size + 255)/256, 256, 0, stream>>>((float*)d_out, out_size);
        return;
    }

    int gq = (E + 15)/16;
    int gw = (E + 3)/4;
    seg_start_kernel<<<(E + 1 + 255)/256, 256, 0, stream>>>(idx_ji, T, seg, E);
    pack_w2<<<32, 256, 0, stream>>>(hkW2, hvW2, kw2t, vw2t);
    q_kernel<<<gq, 128, 0, stream>>>(hqW1, hqb1, hqg, hqb, hqW2, hqb2, h_bond, qf, E);
    p_prep<<<gq, 128, 0, stream>>>(hkW1, h_bond, pos, row, col, P1k, E);
    p_prep<<<gq, 128, 0, stream>>>(hvW1, h_bond, pos, row, col, P1v, E);
    fused_kernel<<<gw, 256, 0, stream>>>(kw2t, vw2t,
        hkW1, hkb1, hkg, hkb,
        hvW1, hvb1, hvg, hvb,
        hvb2, qf, P1k, P1v, pos, seg, idx_kj, idx_k, row, col, (float*)d_out, E);
}